// Round 4
// baseline (303.832 us; speedup 1.0000x reference)
//
#include <hip/hip_runtime.h>
#include <hip/hip_bf16.h>

#define Hh 96
#define Ww 128
#define Cc 21
#define Nn (Hh * Ww)       // 12288
#define RAD 20             // exp(-d^2/18) < 3e-10 beyond d=20
#define WIN (2 * RAD + 1)  // 41
#define COLSZ (Hh * Cc)    // 2016 floats per image column
#define SCOLS 8            // columns staged per LDS pass
#define NSTAGE 6           // 6*8 = 48 >= 41

// One kernel per CRF iteration; block = one output column x (128 blocks).
// Phase A: 6 staged LDS passes over the 41-column halo: coalesced float4
//          column loads -> in-place softmax -> register H-blur accumulation.
// Phase B: vertical 41-tap blur + exact separable nx*ny normalization.
// Phase C: q_new = u - M @ s with M = compat @ (Ws+Wb)   (bilateral kernel is
//          dead code: reference uses spatial_out for both message terms).
// q layout [x][h][c] == output layout (1,W,H,C): last iter writes d_out.
__global__ __launch_bounds__(256) void crf_iter_k(
    const float* __restrict__ qin, int nhwc,
    const float* __restrict__ u,
    const float* __restrict__ Ws, const float* __restrict__ Wb,
    const float* __restrict__ compat,
    float* __restrict__ qout) {
  const int x = blockIdx.x;
  const int tid = threadIdx.x;

  __shared__ float M_ld[Cc * Cc];
  __shared__ float ny_ld[Hh];
  __shared__ float w_ld[RAD + 1];
  // stage buffer 8*2016 (+32 slop for unguarded k=7 reads) = 64.6 KB;
  // phases B/C alias it: tbuf [136][21]=2856 then sbuf [96][21]=2016.
  __shared__ __align__(16) float buf[SCOLS * COLSZ + 32];

  // ---- precompute: blur weights, M; then separable norms from w_ld ----
  if (tid <= RAD) w_ld[tid] = __expf((float)(tid * tid) * (-1.f / 18.f));
  for (int i = tid; i < Cc * Cc; i += 256) {
    int a = i / Cc, b = i % Cc;
    float s = 0.f;
    #pragma unroll
    for (int k = 0; k < Cc; ++k)
      s += compat[a * Cc + k] * (Ws[k * Cc + b] + Wb[k * Cc + b]);
    M_ld[i] = s;
  }
  __syncthreads();
  if (tid < Hh) {
    float s = 0.f;
    #pragma unroll
    for (int d = -RAD; d <= RAD; ++d) {
      int hp = tid + d;
      if (hp >= 0 && hp < Hh) s += w_ld[d < 0 ? -d : d];
    }
    ny_ld[tid] = s;  // tail terms < 3e-10: below fp32 eps of the sum
  }
  float nxv = 0.f;
  #pragma unroll
  for (int d = -RAD; d <= RAD; ++d) {
    int xp = x + d;
    if (xp >= 0 && xp < Ww) nxv += w_ld[d < 0 ? -d : d];
  }

  // ---- Phase A: staged softmax + horizontal blur ----
  float acc[8];
  #pragma unroll
  for (int k = 0; k < 8; ++k) acc[k] = 0.f;

  for (int s = 0; s < NSTAGE; ++s) {
    const int base = s * SCOLS;
    float wj[SCOLS];
    float wsum = 0.f;
    #pragma unroll
    for (int j = 0; j < SCOLS; ++j) {
      int off = base + j;
      int xs = x - RAD + off;
      bool ok = (off < WIN) && (xs >= 0) && (xs < Ww);
      int ad = off - RAD; if (ad < 0) ad = -ad;
      wj[j] = (ok && ad <= RAD) ? w_ld[ad] : 0.f;
      wsum += wj[j];
    }
    if (wsum <= 0.f) continue;  // block-uniform: safe around __syncthreads

    __syncthreads();  // previous stage's accumulate reads complete
    if (!nhwc) {
      // q layout: column is 2016 contiguous floats -> coalesced float4
      for (int idx = tid; idx < SCOLS * (COLSZ / 4); idx += 256) {
        int j = idx / (COLSZ / 4), m4 = idx % (COLSZ / 4);
        int xs = x - RAD + base + j;
        xs = xs < 0 ? 0 : (xs >= Ww ? Ww - 1 : xs);  // weight 0 kills clamps
        float4 v = *(const float4*)(qin + (size_t)xs * COLSZ + m4 * 4);
        *(float4*)(buf + j * COLSZ + m4 * 4) = v;
      }
    } else {
      // u NHWC: per (h) 21-float chunks, near-coalesced scalar loads
      for (int idx = tid; idx < SCOLS * COLSZ; idx += 256) {
        int j = idx / COLSZ, m = idx % COLSZ;
        int xs = x - RAD + base + j;
        xs = xs < 0 ? 0 : (xs >= Ww ? Ww - 1 : xs);
        int h = m / Cc, c = m % Cc;
        buf[j * COLSZ + m] = qin[((size_t)h * Ww + xs) * Cc + c];
      }
    }
    __syncthreads();

    // in-place softmax: 8 cols * 96 h = 768 private 21-float chunks
    #pragma unroll
    for (int r = 0; r < 3; ++r) {
      int t = tid + 256 * r;
      int j = t / Hh, h = t % Hh;
      float* p = buf + j * COLSZ + h * Cc;
      float v[Cc];
      float m = -1e30f;
      #pragma unroll
      for (int c = 0; c < Cc; ++c) { v[c] = p[c]; m = fmaxf(m, v[c]); }
      float ssum = 0.f;
      #pragma unroll
      for (int c = 0; c < Cc; ++c) { v[c] = __expf(v[c] - m); ssum += v[c]; }
      float inv = 1.f / ssum;
      #pragma unroll
      for (int c = 0; c < Cc; ++c) p[c] = v[c] * inv;
    }
    __syncthreads();

    // accumulate: lanes contiguous in i -> conflict-free LDS reads
    #pragma unroll
    for (int j = 0; j < SCOLS; ++j) {
      float wv = wj[j];
      #pragma unroll
      for (int k = 0; k < 8; ++k)
        acc[k] += wv * buf[j * COLSZ + tid + 256 * k];
    }
  }

  // ---- Phase B: vertical blur + normalize ----
  __syncthreads();  // all accumulate reads done; buf is now tbuf/sbuf
  float* tbuf = buf;             // [(RAD+Hh+RAD)][Cc] = 2856, zero-padded
  float* sbuf = buf + 136 * Cc;  // [Hh][Cc] = 2016
  for (int i = tid; i < RAD * Cc; i += 256) {
    tbuf[i] = 0.f;
    tbuf[(RAD + Hh) * Cc + i] = 0.f;
  }
  #pragma unroll
  for (int k = 0; k < 8; ++k) {
    int i = tid + 256 * k;
    if (i < COLSZ) tbuf[RAD * Cc + i] = acc[k];
  }
  __syncthreads();

  float sres[8];
  #pragma unroll
  for (int k = 0; k < 8; ++k) {
    int i = tid + 256 * k;
    if (i < COLSZ) {
      int h = i / Cc;
      float sacc = w_ld[0] * tbuf[RAD * Cc + i];
      #pragma unroll
      for (int d = 1; d <= RAD; ++d)
        sacc += w_ld[d] * (tbuf[(RAD - d) * Cc + i] + tbuf[(RAD + d) * Cc + i]);
      sres[k] = sacc / (nxv * ny_ld[h]);
    } else {
      sres[k] = 0.f;
    }
  }
  __syncthreads();  // tbuf reads done before sbuf writes? (disjoint, but cheap)
  #pragma unroll
  for (int k = 0; k < 8; ++k) {
    int i = tid + 256 * k;
    if (i < COLSZ) sbuf[i] = sres[k];
  }
  __syncthreads();

  // ---- Phase C: q_new = u - M @ s ; coalesced writes in [x][h][c] ----
  #pragma unroll
  for (int k = 0; k < 8; ++k) {
    int i = tid + 256 * k;
    if (i < COLSZ) {
      int h = i / Cc, c = i % Cc;
      float a = 0.f;
      #pragma unroll
      for (int b = 0; b < Cc; ++b) a += M_ld[c * Cc + b] * sbuf[h * Cc + b];
      qout[(size_t)x * COLSZ + i] = u[((size_t)h * Ww + x) * Cc + c] - a;
    }
  }
}

// ---------------------------------------------------------------------------
extern "C" void kernel_launch(void* const* d_in, const int* in_sizes, int n_in,
                              void* d_out, int out_size, void* d_ws, size_t ws_size,
                              hipStream_t stream) {
  const float* u      = (const float*)d_in[0];  // (1,H,W,C)
  // d_in[1] = rgb: DEAD (replicated source bug uses spatial_out twice)
  const float* Ws     = (const float*)d_in[2];
  const float* Wb     = (const float*)d_in[3];
  const float* compat = (const float*)d_in[4];
  float* out = (float*)d_out;

  float* qa = (float*)d_ws;       // [W][H][C]
  float* qb = qa + Cc * Nn;

  crf_iter_k<<<Ww, 256, 0, stream>>>(u,  1, u, Ws, Wb, compat, qa);
  crf_iter_k<<<Ww, 256, 0, stream>>>(qa, 0, u, Ws, Wb, compat, qb);
  crf_iter_k<<<Ww, 256, 0, stream>>>(qb, 0, u, Ws, Wb, compat, qa);
  crf_iter_k<<<Ww, 256, 0, stream>>>(qa, 0, u, Ws, Wb, compat, qb);
  crf_iter_k<<<Ww, 256, 0, stream>>>(qb, 0, u, Ws, Wb, compat, out);
}

// Round 5
// 161.292 us; speedup vs baseline: 1.8837x; 1.8837x over previous
//
#include <hip/hip_runtime.h>
#include <hip/hip_bf16.h>

#define Hh 96
#define Ww 128
#define Cc 21
#define Nn (Hh * Ww)       // 12288
#define COLSZ (Hh * Cc)    // 2016 floats per image column
#define NF4 (COLSZ / 4)    // 504 float4 per column
#define RAD 20             // exp(-d^2/18) < 3e-10 beyond d=20
#define TSTR 140           // tbuf per-channel stride (136 used, mult-of-4)

// ---------------------------------------------------------------------------
// p0 = softmax(u) over classes, emitted in [x][h][c] column layout.
// ---------------------------------------------------------------------------
__global__ __launch_bounds__(256) void softmax0_k(
    const float* __restrict__ u, float* __restrict__ p0) {
  const int x = blockIdx.x, tid = threadIdx.x;
  __shared__ __align__(16) float qbuf[COLSZ];
  #pragma unroll
  for (int k = 0; k < 8; ++k) {
    int i = tid + 256 * k;
    if (i < COLSZ) {
      int h = i / Cc, c = i % Cc;
      qbuf[i] = u[((size_t)h * Ww + x) * Cc + c];
    }
  }
  __syncthreads();
  if (tid < Hh) {
    float* p = qbuf + tid * Cc;
    float v[Cc];
    float m = -1e30f;
    #pragma unroll
    for (int c = 0; c < Cc; ++c) { v[c] = p[c]; m = fmaxf(m, v[c]); }
    float s = 0.f;
    #pragma unroll
    for (int c = 0; c < Cc; ++c) { v[c] = __expf(v[c] - m); s += v[c]; }
    float inv = 1.f / s;
    #pragma unroll
    for (int c = 0; c < Cc; ++c) p[c] = v[c] * inv;
  }
  __syncthreads();
  #pragma unroll
  for (int k = 0; k < 2; ++k) {
    int f = tid + 256 * k;
    if (f < NF4)
      *(float4*)(p0 + (size_t)x * COLSZ + 4 * f) = *(const float4*)(qbuf + 4 * f);
  }
}

// ---------------------------------------------------------------------------
// One CRF iteration; block = column x. Ingests already-softmaxed p.
// A: 41-tap H-blur straight from global (coalesced float4, no redundancy).
// B: 41-tap V-blur in LDS + separable nx*ny normalization.
// C: q = u - M@s (M = compat@(Ws+Wb); bilateral term is dead code in ref),
//    then p_next = softmax(q) over c (block-local), or raw q if last.
// ---------------------------------------------------------------------------
__global__ __launch_bounds__(256) void crf_iter_k(
    const float* __restrict__ pin, const float* __restrict__ u,
    const float* __restrict__ Ws, const float* __restrict__ Wb,
    const float* __restrict__ compat, float* __restrict__ outp, int last) {
  const int x = blockIdx.x, tid = threadIdx.x;

  __shared__ float w_ld[RAD + 1];
  __shared__ float ny_ld[Hh];
  __shared__ float M_ld[Cc * Cc];
  __shared__ float wsum_ld[Cc * Cc];
  __shared__ float cm_ld[Cc * Cc];
  __shared__ __align__(16) float tbuf[Cc * TSTR];  // [c][20|96|20] padded
  __shared__ __align__(16) float sbuf[COLSZ];      // [h][c]
  __shared__ __align__(16) float qbuf[COLSZ];      // [h][c]

  // ---- early u prefetch (needed only in phase C; hides gather latency) ----
  float uval[8];
  #pragma unroll
  for (int k = 0; k < 8; ++k) {
    int i = tid + 256 * k;
    uval[k] = (i < COLSZ) ? u[((size_t)(i / Cc) * Ww + x) * Cc + (i % Cc)] : 0.f;
  }

  // ---- per-block precompute (coalesced staging, no gathers) ----
  if (tid <= RAD) w_ld[tid] = __expf((float)(tid * tid) * (-1.f / 18.f));
  #pragma unroll
  for (int k = 0; k < 2; ++k) {
    int i = tid + 256 * k;
    if (i < Cc * Cc) { wsum_ld[i] = Ws[i] + Wb[i]; cm_ld[i] = compat[i]; }
  }
  // zero vertical pads of tbuf (disjoint from all other writes before sync)
  for (int i = tid; i < Cc * 2 * RAD; i += 256) {
    int c = i / (2 * RAD), g = i % (2 * RAD);
    tbuf[c * TSTR + (g < RAD ? g : Hh + g)] = 0.f;
  }
  __syncthreads();
  #pragma unroll
  for (int k = 0; k < 2; ++k) {
    int i = tid + 256 * k;
    if (i < Cc * Cc) {
      int a = i / Cc, b = i % Cc;
      float s = 0.f;
      #pragma unroll
      for (int kk = 0; kk < Cc; ++kk) s += cm_ld[a * Cc + kk] * wsum_ld[kk * Cc + b];
      M_ld[i] = s;
    }
  }
  if (tid < Hh) {
    float s = 0.f;
    #pragma unroll
    for (int d = -RAD; d <= RAD; ++d) {
      int hp = tid + d;
      if (hp >= 0 && hp < Hh) s += w_ld[d < 0 ? -d : d];
    }
    ny_ld[tid] = s;  // truncated tail < 3e-10: below fp32 eps of the sum
  }
  float nxv = 0.f;
  #pragma unroll
  for (int d = -RAD; d <= RAD; ++d) {
    int xp = x + d;
    if (xp >= 0 && xp < Ww) nxv += w_ld[d < 0 ? -d : d];
  }

  // ---- Phase A: H-blur from global p (coalesced float4, no softmax) ----
  float4 acc0 = {0.f, 0.f, 0.f, 0.f}, acc1 = {0.f, 0.f, 0.f, 0.f};
  const int f0 = tid, f1 = tid + 256;
  for (int xs = x - RAD; xs <= x + RAD; ++xs) {  // bounds block-uniform
    if (xs < 0 || xs >= Ww) continue;
    int ad = xs - x; if (ad < 0) ad = -ad;
    float wv = w_ld[ad];
    const float* col = pin + (size_t)xs * COLSZ;
    float4 v0 = *(const float4*)(col + 4 * f0);
    acc0.x += wv * v0.x; acc0.y += wv * v0.y;
    acc0.z += wv * v0.z; acc0.w += wv * v0.w;
    if (f1 < NF4) {
      float4 v1 = *(const float4*)(col + 4 * f1);
      acc1.x += wv * v1.x; acc1.y += wv * v1.y;
      acc1.z += wv * v1.z; acc1.w += wv * v1.w;
    }
  }

  // scatter H-blur result into transposed padded tbuf [c][RAD+h]
  {
    float a0[4] = {acc0.x, acc0.y, acc0.z, acc0.w};
    #pragma unroll
    for (int e = 0; e < 4; ++e) {
      int i = 4 * f0 + e;
      tbuf[(i % Cc) * TSTR + RAD + (i / Cc)] = a0[e];
    }
    if (f1 < NF4) {
      float a1[4] = {acc1.x, acc1.y, acc1.z, acc1.w};
      #pragma unroll
      for (int e = 0; e < 4; ++e) {
        int i = 4 * f1 + e;
        tbuf[(i % Cc) * TSTR + RAD + (i / Cc)] = a1[e];
      }
    }
  }
  __syncthreads();

  // ---- Phase B: V-blur (aligned float4 LDS reads) + normalize ----
  #pragma unroll
  for (int kt = 0; kt < 2; ++kt) {
    int tau = tid + 256 * kt;
    if (tau < NF4) {             // 504 = 21 c * 24 h-quads
      int c = tau / 24, q = tau % 24;
      int h0 = 4 * q;
      const float* base = tbuf + c * TSTR + h0;  // padded idx of h0-RAD
      float r[4] = {0.f, 0.f, 0.f, 0.f};
      #pragma unroll
      for (int j = 0; j < 11; ++j) {
        float4 tv = *(const float4*)(base + 4 * j);
        float tvv[4] = {tv.x, tv.y, tv.z, tv.w};
        #pragma unroll
        for (int kk = 0; kk < 4; ++kk) {
          #pragma unroll
          for (int o = 0; o < 4; ++o) {
            int d = 4 * j + kk - RAD - o;  // compile-time after unroll
            int ad = d < 0 ? -d : d;
            if (ad <= RAD) r[o] += w_ld[ad] * tvv[kk];
          }
        }
      }
      #pragma unroll
      for (int o = 0; o < 4; ++o)
        sbuf[(h0 + o) * Cc + c] = r[o] / (nxv * ny_ld[h0 + o]);
    }
  }
  __syncthreads();

  // ---- Phase C: q = u - M@s, then softmax (or raw q if last) ----
  #pragma unroll
  for (int k = 0; k < 8; ++k) {
    int i = tid + 256 * k;
    if (i < COLSZ) {
      int h = i / Cc, c = i % Cc;
      float a = 0.f;
      #pragma unroll
      for (int b = 0; b < Cc; ++b) a += M_ld[c * Cc + b] * sbuf[h * Cc + b];
      qbuf[i] = uval[k] - a;
    }
  }
  __syncthreads();
  if (!last && tid < Hh) {       // `last` is uniform
    float* p = qbuf + tid * Cc;
    float v[Cc];
    float m = -1e30f;
    #pragma unroll
    for (int c = 0; c < Cc; ++c) { v[c] = p[c]; m = fmaxf(m, v[c]); }
    float s = 0.f;
    #pragma unroll
    for (int c = 0; c < Cc; ++c) { v[c] = __expf(v[c] - m); s += v[c]; }
    float inv = 1.f / s;
    #pragma unroll
    for (int c = 0; c < Cc; ++c) p[c] = v[c] * inv;
  }
  __syncthreads();
  #pragma unroll
  for (int k = 0; k < 2; ++k) {
    int f = tid + 256 * k;
    if (f < NF4)
      *(float4*)(outp + (size_t)x * COLSZ + 4 * f) = *(const float4*)(qbuf + 4 * f);
  }
}

// ---------------------------------------------------------------------------
extern "C" void kernel_launch(void* const* d_in, const int* in_sizes, int n_in,
                              void* d_out, int out_size, void* d_ws, size_t ws_size,
                              hipStream_t stream) {
  const float* u      = (const float*)d_in[0];  // (1,H,W,C)
  // d_in[1] = rgb: DEAD (replicated source bug uses spatial_out twice)
  const float* Ws     = (const float*)d_in[2];
  const float* Wb     = (const float*)d_in[3];
  const float* compat = (const float*)d_in[4];
  float* out = (float*)d_out;

  float* pa = (float*)d_ws;        // [W][H][C] 258048 floats
  float* pb = pa + (size_t)Cc * Nn;

  softmax0_k<<<Ww, 256, 0, stream>>>(u, pa);
  crf_iter_k<<<Ww, 256, 0, stream>>>(pa, u, Ws, Wb, compat, pb, 0);
  crf_iter_k<<<Ww, 256, 0, stream>>>(pb, u, Ws, Wb, compat, pa, 0);
  crf_iter_k<<<Ww, 256, 0, stream>>>(pa, u, Ws, Wb, compat, pb, 0);
  crf_iter_k<<<Ww, 256, 0, stream>>>(pb, u, Ws, Wb, compat, pa, 0);
  crf_iter_k<<<Ww, 256, 0, stream>>>(pa, u, Ws, Wb, compat, out, 1);
}

// Round 6
// 142.865 us; speedup vs baseline: 2.1267x; 1.1290x over previous
//
#include <hip/hip_runtime.h>
#include <hip/hip_bf16.h>

#define Hh 96
#define Ww 128
#define Cc 21
#define Nn (Hh * Ww)       // 12288
#define COLSZ (Hh * Cc)    // 2016 floats per image column
#define NF4 (COLSZ / 4)    // 504 float4 per column
#define RAD 20             // exp(-d^2/18) < 3e-10 beyond d=20
#define TSTR 140           // tbuf per-channel stride (136 used, mult-of-4)
#define NT 512             // threads per block: 8 waves -> 2 waves/SIMD

// ---------------------------------------------------------------------------
// p0 = softmax(u) over classes, emitted in [x][h][c] column layout.
// ---------------------------------------------------------------------------
__global__ __launch_bounds__(NT) void softmax0_k(
    const float* __restrict__ u, float* __restrict__ p0) {
  const int x = blockIdx.x, tid = threadIdx.x;
  __shared__ __align__(16) float qbuf[COLSZ];
  #pragma unroll
  for (int k = 0; k < 4; ++k) {
    int i = tid + NT * k;
    if (i < COLSZ) {
      int h = i / Cc, c = i % Cc;
      qbuf[i] = u[((size_t)h * Ww + x) * Cc + c];
    }
  }
  __syncthreads();
  if (tid < Hh) {
    float* p = qbuf + tid * Cc;
    float v[Cc];
    float m = -1e30f;
    #pragma unroll
    for (int c = 0; c < Cc; ++c) { v[c] = p[c]; m = fmaxf(m, v[c]); }
    float s = 0.f;
    #pragma unroll
    for (int c = 0; c < Cc; ++c) { v[c] = __expf(v[c] - m); s += v[c]; }
    float inv = 1.f / s;
    #pragma unroll
    for (int c = 0; c < Cc; ++c) p[c] = v[c] * inv;
  }
  __syncthreads();
  if (tid < NF4)
    *(float4*)(p0 + (size_t)x * COLSZ + 4 * tid) = *(const float4*)(qbuf + 4 * tid);
}

// ---------------------------------------------------------------------------
// One CRF iteration; block = column x, 512 threads. Ingests softmaxed p.
// A: 41-tap H-blur straight from global (1 float4/thread, coalesced).
// B: 41-tap V-blur in LDS + separable nx*ny normalization.
// C: q = u - M@s (M = compat@(Ws+Wb); bilateral term is dead code in ref),
//    then p_next = softmax(q) over c, or raw q if last iteration.
// ---------------------------------------------------------------------------
__global__ __launch_bounds__(NT) void crf_iter_k(
    const float* __restrict__ pin, const float* __restrict__ u,
    const float* __restrict__ Ws, const float* __restrict__ Wb,
    const float* __restrict__ compat, float* __restrict__ outp, int last) {
  const int x = blockIdx.x, tid = threadIdx.x;

  __shared__ float w_ld[RAD + 1];
  __shared__ float ny_ld[Hh];
  __shared__ float M_ld[Cc * Cc];
  __shared__ float wsum_ld[Cc * Cc];
  __shared__ float cm_ld[Cc * Cc];
  __shared__ __align__(16) float tbuf[Cc * TSTR];  // [c][20|96|20] padded
  __shared__ __align__(16) float sbuf[COLSZ];      // [h][c]
  __shared__ __align__(16) float qbuf[COLSZ];      // [h][c]

  // ---- early u prefetch (only needed in Phase C; hides gather latency) ----
  float uval[4];
  #pragma unroll
  for (int k = 0; k < 4; ++k) {
    int i = tid + NT * k;
    uval[k] = (i < COLSZ) ? u[((size_t)(i / Cc) * Ww + x) * Cc + (i % Cc)] : 0.f;
  }

  // ---- per-block precompute ----
  if (tid <= RAD) w_ld[tid] = __expf((float)(tid * tid) * (-1.f / 18.f));
  if (tid < Cc * Cc) { wsum_ld[tid] = Ws[tid] + Wb[tid]; cm_ld[tid] = compat[tid]; }
  // zero vertical pads of tbuf (disjoint from later writes before sync)
  for (int i = tid; i < Cc * 2 * RAD; i += NT) {
    int c = i / (2 * RAD), g = i % (2 * RAD);
    tbuf[c * TSTR + (g < RAD ? g : Hh + g)] = 0.f;
  }
  __syncthreads();
  if (tid < Cc * Cc) {
    int a = tid / Cc, b = tid % Cc;
    float s = 0.f;
    #pragma unroll
    for (int kk = 0; kk < Cc; ++kk) s += cm_ld[a * Cc + kk] * wsum_ld[kk * Cc + b];
    M_ld[tid] = s;  // consumed in Phase C (covered by the pre-Phase-B barrier)
  }
  if (tid < Hh) {
    float s = 0.f;
    #pragma unroll
    for (int d = -RAD; d <= RAD; ++d) {
      int hp = tid + d;
      if (hp >= 0 && hp < Hh) s += w_ld[d < 0 ? -d : d];
    }
    ny_ld[tid] = s;  // truncated tail < 3e-10: below fp32 eps of the sum
  }
  float nxv = 0.f;
  #pragma unroll
  for (int d = -RAD; d <= RAD; ++d) {
    int xp = x + d;
    if (xp >= 0 && xp < Ww) nxv += w_ld[d < 0 ? -d : d];
  }

  // ---- Phase A: H-blur from global p (1 float4/thread, coalesced) ----
  float4 acc = {0.f, 0.f, 0.f, 0.f};
  const bool af = (tid < NF4);
  for (int xs = x - RAD; xs <= x + RAD; ++xs) {  // bounds block-uniform
    if (xs < 0 || xs >= Ww) continue;
    int ad = xs - x; if (ad < 0) ad = -ad;
    float wv = w_ld[ad];
    if (af) {
      float4 v = *(const float4*)(pin + (size_t)xs * COLSZ + 4 * tid);
      acc.x += wv * v.x; acc.y += wv * v.y;
      acc.z += wv * v.z; acc.w += wv * v.w;
    }
  }
  if (af) {  // scatter into transposed padded tbuf [c][RAD+h]
    float a4[4] = {acc.x, acc.y, acc.z, acc.w};
    #pragma unroll
    for (int e = 0; e < 4; ++e) {
      int i = 4 * tid + e;
      tbuf[(i % Cc) * TSTR + RAD + (i / Cc)] = a4[e];
    }
  }
  __syncthreads();

  // ---- Phase B: V-blur (aligned float4 LDS reads) + normalize ----
  if (tid < NF4) {               // 504 = 21 c * 24 h-quads
    int c = tid / 24, q = tid % 24;
    int h0 = 4 * q;
    const float* base = tbuf + c * TSTR + h0;  // padded idx of h0-RAD
    float r[4] = {0.f, 0.f, 0.f, 0.f};
    #pragma unroll
    for (int j = 0; j < 11; ++j) {
      float4 tv = *(const float4*)(base + 4 * j);
      float tvv[4] = {tv.x, tv.y, tv.z, tv.w};
      #pragma unroll
      for (int kk = 0; kk < 4; ++kk) {
        #pragma unroll
        for (int o = 0; o < 4; ++o) {
          int d = 4 * j + kk - RAD - o;  // compile-time after unroll
          int ad = d < 0 ? -d : d;
          if (ad <= RAD) r[o] += w_ld[ad] * tvv[kk];
        }
      }
    }
    #pragma unroll
    for (int o = 0; o < 4; ++o)
      sbuf[(h0 + o) * Cc + c] = r[o] / (nxv * ny_ld[h0 + o]);
  }
  __syncthreads();

  // ---- Phase C: q = u - M@s, then softmax (or raw q if last) ----
  #pragma unroll
  for (int k = 0; k < 4; ++k) {
    int i = tid + NT * k;
    if (i < COLSZ) {
      int h = i / Cc, c = i % Cc;
      float a = 0.f;
      #pragma unroll
      for (int b = 0; b < Cc; ++b) a += M_ld[c * Cc + b] * sbuf[h * Cc + b];
      qbuf[i] = uval[k] - a;
    }
  }
  __syncthreads();
  if (!last && tid < Hh) {       // `last` is block-uniform
    float* p = qbuf + tid * Cc;
    float v[Cc];
    float m = -1e30f;
    #pragma unroll
    for (int c = 0; c < Cc; ++c) { v[c] = p[c]; m = fmaxf(m, v[c]); }
    float s = 0.f;
    #pragma unroll
    for (int c = 0; c < Cc; ++c) { v[c] = __expf(v[c] - m); s += v[c]; }
    float inv = 1.f / s;
    #pragma unroll
    for (int c = 0; c < Cc; ++c) p[c] = v[c] * inv;
  }
  __syncthreads();
  if (tid < NF4)
    *(float4*)(outp + (size_t)x * COLSZ + 4 * tid) = *(const float4*)(qbuf + 4 * tid);
}

// ---------------------------------------------------------------------------
extern "C" void kernel_launch(void* const* d_in, const int* in_sizes, int n_in,
                              void* d_out, int out_size, void* d_ws, size_t ws_size,
                              hipStream_t stream) {
  const float* u      = (const float*)d_in[0];  // (1,H,W,C)
  // d_in[1] = rgb: DEAD (replicated source bug uses spatial_out twice)
  const float* Ws     = (const float*)d_in[2];
  const float* Wb     = (const float*)d_in[3];
  const float* compat = (const float*)d_in[4];
  float* out = (float*)d_out;

  float* pa = (float*)d_ws;        // [W][H][C] 258048 floats
  float* pb = pa + (size_t)Cc * Nn;

  softmax0_k<<<Ww, NT, 0, stream>>>(u, pa);
  crf_iter_k<<<Ww, NT, 0, stream>>>(pa, u, Ws, Wb, compat, pb, 0);
  crf_iter_k<<<Ww, NT, 0, stream>>>(pb, u, Ws, Wb, compat, pa, 0);
  crf_iter_k<<<Ww, NT, 0, stream>>>(pa, u, Ws, Wb, compat, pb, 0);
  crf_iter_k<<<Ww, NT, 0, stream>>>(pb, u, Ws, Wb, compat, pa, 0);
  crf_iter_k<<<Ww, NT, 0, stream>>>(pa, u, Ws, Wb, compat, out, 1);
}